// Round 9
// baseline (171.894 us; speedup 1.0000x reference)
//
#include <hip/hip_runtime.h>
#include <hip/hip_bf16.h>

// DCNv2: B=4, C=64, H=W=128, O=64, KS=3, N=9, PAD=1. I/O float32.
#define BB 4
#define CC 64
#define HH 128
#define WW 128
#define OO 64
#define NN 9
#define HW 16384
#define HP 130
#define WP 130

// ---- ws layout (float-slot offsets) ----
// 0        wpmb bf16 [32][576]   (rows 0..17 w_p, 18..26 w_m, 27..31 zero)
// 9216     bias fp32 (18 b_p then 9 b_m)
// 9248     wcb  bf16 [o(64)][K(576)], K = kt*64+c
// 27680    xt   bf16 [b][hw][c]
#define WPMB_F  0
#define BPM_OFF 9216
#define WCB_F   9248
#define XT_F    27680

typedef __attribute__((ext_vector_type(8))) short s8v;
typedef __attribute__((ext_vector_type(8))) unsigned short u8v;
typedef __attribute__((ext_vector_type(4))) float f4v;

__device__ __forceinline__ unsigned short f2bu(float f) {   // fp32 -> bf16 bits (RNE)
    unsigned int b = __float_as_uint(f);
    return (unsigned short)((b + 0x7FFFu + ((b >> 16) & 1u)) >> 16);
}
__device__ __forceinline__ float bu2f(unsigned short u) {
    return __uint_as_float(((unsigned int)u) << 16);
}

#define MF(a, bb, c) __builtin_amdgcn_mfma_f32_16x16x32_bf16(a, bb, c, 0, 0, 0)

// blocks [0,1024): NCHW fp32 -> NHWC bf16 transpose via LDS tile (XCD-swizzled
// to match k_main's consumer mapping). blocks [1024,1248): weight prep.
__global__ void __launch_bounds__(256) k_pxt(const float* __restrict__ x,
                                             const float* __restrict__ wp,
                                             const float* __restrict__ bp,
                                             const float* __restrict__ wm,
                                             const float* __restrict__ bm,
                                             const float* __restrict__ wcv,
                                             float* __restrict__ ws) {
    int blk = blockIdx.x;
    int t = threadIdx.x;
    if (blk >= 1024) {                       // ---- weight prep path ----
        int tid = (blk - 1024) * 256 + t;
        if (tid < 18432) {                   // wpmb [32][576]
            int r = tid / 576;
            int kk = tid % 576;              // kk = kt*64 + c
            int kt = kk >> 6;
            int c = kk & 63;
            int dy = kt / 3, dx = kt % 3;
            float v = 0.f;
            if (r < 18)       v = wp[((r * 64 + c) * 3 + dy) * 3 + dx];
            else if (r < 27)  v = wm[(((r - 18) * 64 + c) * 3 + dy) * 3 + dx];
            ((unsigned short*)(ws + WPMB_F))[tid] = f2bu(v);
        } else if (tid < 18459) {
            int i = tid - 18432;
            ws[BPM_OFF + i] = (i < 18) ? bp[i] : bm[i - 18];
        } else if (tid >= 20480) {           // wcb [64][576], tid < 57344 by grid
            int d = tid - 20480;
            int o = d / 576;
            int kk = d % 576;
            int kt = kk >> 6;
            int c = kk & 63;
            ((unsigned short*)(ws + WCB_F))[o * 576 + kk] = f2bu(wcv[(o * 64 + c) * 9 + kt]);
        }
        return;
    }
    // ---- transpose: block = 64 hw x 64 ch, tile stored [hw][c] ----
    __shared__ unsigned short tile[64][72];   // 16B-aligned rows (144B)
    int sb = ((blk & 7) << 7) | (blk >> 3);   // XCD-chunked bijection on [0,1024)
    int b = sb >> 8;
    int hw0 = (sb & 255) * 64;
    unsigned short* xt = (unsigned short*)(ws + XT_F);

#pragma unroll
    for (int p = 0; p < 4; p++) {            // coalesced float4 reads: 256B/instr per c-row
        int c = p * 16 + (t >> 4);
        int h4 = (t & 15) * 4;
        float4 v = *(const float4*)(x + ((size_t)(b * 64 + c)) * HW + hw0 + h4);
        tile[h4 + 0][c] = f2bu(v.x);
        tile[h4 + 1][c] = f2bu(v.y);
        tile[h4 + 2][c] = f2bu(v.z);
        tile[h4 + 3][c] = f2bu(v.w);
    }
    __syncthreads();
#pragma unroll
    for (int p = 0; p < 2; p++) {            // contiguous 16B/lane stores: 1KB/wave
        int hw = p * 32 + (t >> 3);
        int cb = (t & 7) * 8;
        u8v o = *(const u8v*)(&tile[hw][cb]);
        *(u8v*)(xt + ((size_t)(b * HW + hw0 + hw)) * 64 + cb) = o;
    }
}

// Fused offset-conv + sampler + einsum. ONE WAVE PER BLOCK (64 threads, 4096
// blocks) for max TLP: VGPR=64 allows 8 waves/SIMD; LDS 1.7KB/block allows 32
// blocks/CU. Wave-synchronous, register-direct B, depth-2 issue order (compiler
// may collapse to depth-1 — TLP now does the latency hiding instead of ILP).
__global__ void __launch_bounds__(64) k_main(const float* __restrict__ ws,
                                             float* __restrict__ out) {
    __shared__ float pxmL[3][NN][16];        // [{px,py,m}][tap][pixel]

    int lane = threadIdx.x & 63;
    int ln15 = lane & 15;
    int quad = lane >> 4;

    int braw = blockIdx.x;                   // 4096 = 8 XCD * 512: chunked swizzle
    int blk = ((braw & 7) << 9) | (braw >> 3);
    int b = blk >> 10;                       // 1024 16-pixel tiles per image
    int hw0 = (blk & 1023) * 16;             // this wave's 16-pixel base

    const unsigned short* wpmb = (const unsigned short*)(ws + WPMB_F);
    const unsigned short* wcb  = (const unsigned short*)(ws + WCB_F);
    const unsigned short* xtb  = (const unsigned short*)(ws + XT_F) + (size_t)b * HW * 64;
    const float* bpm = ws + BPM_OFF;

    int gp = hw0 + ln15;                     // this lane's pixel (B-frag column)
    int ph = gp >> 7, pw = gp & 127;
    int c0 = quad * 8;                       // this lane's k-slice base (A and B)

    const s8v zs = (s8v){0, 0, 0, 0, 0, 0, 0, 0};
    const f4v zf = (f4v){0.f, 0.f, 0.f, 0.f};

    // ================= PHASE 1: offset/modulation GEMM (M=27, K=576) =================
    {
        f4v acc1[2];
        acc1[0] = zf;
        acc1[1] = zf;
        s8v pB[2][2];                        // depth-2 B double buffer (static idx)

#define PLOAD1(SET, KT) { \
            int dy_ = (KT) / 3, dx_ = (KT) % 3; \
            int h2_ = ph + dy_ - 1, w2_ = pw + dx_ - 1; \
            s8v t0_ = zs, t1_ = zs; \
            if (((unsigned)h2_ < 128u) && ((unsigned)w2_ < 128u)) { \
                const unsigned short* s_ = xtb + (size_t)(h2_ * 128 + w2_) * 64; \
                t0_ = *(const s8v*)(s_ + c0); \
                t1_ = *(const s8v*)(s_ + 32 + c0); \
            } \
            pB[SET][0] = t0_; pB[SET][1] = t1_; }

        PLOAD1(0, 0);
        PLOAD1(1, 1);
#pragma unroll
        for (int kt = 0; kt < 9; kt++) {
            const unsigned short* a = wpmb + ln15 * 576 + kt * 64;
            s8v a00 = *(const s8v*)(a + c0);
            s8v a01 = *(const s8v*)(a + 32 + c0);
            s8v a10 = *(const s8v*)(a + 16 * 576 + c0);
            s8v a11 = *(const s8v*)(a + 16 * 576 + 32 + c0);
            acc1[0] = MF(a00, pB[kt & 1][0], acc1[0]);
            acc1[1] = MF(a10, pB[kt & 1][0], acc1[1]);
            acc1[0] = MF(a01, pB[kt & 1][1], acc1[0]);
            acc1[1] = MF(a11, pB[kt & 1][1], acc1[1]);
            if (kt < 7) PLOAD1(kt & 1, kt + 2);   // in flight for 2 iterations
        }
        // epilogue -> LDS pxm. pixel = ln15, oc = mt*16 + quad*4 + r
#pragma unroll
        for (int mt = 0; mt < 2; mt++) {
#pragma unroll
            for (int r = 0; r < 4; r++) {
                int oc = mt * 16 + quad * 4 + r;
                if (oc < 27) {
                    float v = (mt ? acc1[1][r] : acc1[0][r]) + bpm[oc];
                    if (oc < 9) {
                        pxmL[0][oc][ln15] = v + (float)(oc / 3 - 1) + (float)(ph + 1);
                    } else if (oc < 18) {
                        int k = oc - 9;
                        pxmL[1][k][ln15] = v + (float)(k % 3 - 1) + (float)(pw + 1);
                    } else {
                        int k = oc - 18;
                        pxmL[2][k][ln15] = 1.f / (1.f + __expf(-v));
                    }
                }
            }
        }
    }
    __builtin_amdgcn_wave_barrier();

    // ================= PHASE 2: sample + einsum GEMM (M=64, K=576) =================
    f4v acc[4];
#pragma unroll
    for (int mt = 0; mt < 4; mt++) acc[mt] = zf;

    auto desc = [&](int kt, float& g0, float& g1, float& g2, float& g3,
                    const unsigned short*& q0, const unsigned short*& q1,
                    const unsigned short*& q2, const unsigned short*& q3) {
        float px = pxmL[0][kt][ln15];
        float py = pxmL[1][kt][ln15];
        float mk = pxmL[2][kt][ln15];
        float fx = floorf(px), fy = floorf(py);
        float pxc = fminf(fmaxf(px, 0.f), (float)(HP - 1));
        float pyc = fminf(fmaxf(py, 0.f), (float)(WP - 1));
        int qltx = (int)fminf(fmaxf(fx, 0.f), (float)(HP - 1));
        int qlty = (int)fminf(fmaxf(fy, 0.f), (float)(WP - 1));
        int qrbx = (int)fminf(fmaxf(fx + 1.f, 0.f), (float)(HP - 1));
        int qrby = (int)fminf(fmaxf(fy + 1.f, 0.f), (float)(WP - 1));

        float gltx = 1.f + ((float)qltx - pxc);
        float glty = 1.f + ((float)qlty - pyc);
        float grbx = 1.f - ((float)qrbx - pxc);
        float grby = 1.f - ((float)qrby - pyc);

        bool vlx = (qltx >= 1) && (qltx <= HH);
        bool vly = (qlty >= 1) && (qlty <= WW);
        bool vrx = (qrbx >= 1) && (qrbx <= HH);
        bool vry = (qrby >= 1) && (qrby <= WW);
        g0 = (vlx && vly) ? gltx * glty * mk : 0.f;
        g1 = (vrx && vry) ? grbx * grby * mk : 0.f;
        g2 = (vlx && vry) ? gltx * grby * mk : 0.f;
        g3 = (vrx && vly) ? grbx * glty * mk : 0.f;

        int xlt = min(max(qltx - 1, 0), HH - 1);
        int ylt = min(max(qlty - 1, 0), WW - 1);
        int xrb = min(max(qrbx - 1, 0), HH - 1);
        int yrb = min(max(qrby - 1, 0), WW - 1);
        q0 = xtb + (size_t)(xlt * WW + ylt) * 64;
        q1 = xtb + (size_t)(xrb * WW + yrb) * 64;
        q2 = xtb + (size_t)(xlt * WW + yrb) * 64;
        q3 = xtb + (size_t)(xrb * WW + ylt) * 64;
    };

    u8v eg[2][8];       // depth-2 gather double buffer (static idx after unroll)
    float gg[2][4];
    s8v bf0, bf1;       // current blended B-fragment

#define GLOAD(SET, KT) { \
        const unsigned short *q0_, *q1_, *q2_, *q3_; \
        desc(KT, gg[SET][0], gg[SET][1], gg[SET][2], gg[SET][3], q0_, q1_, q2_, q3_); \
        eg[SET][0] = *(const u8v*)(q0_ + c0);      eg[SET][1] = *(const u8v*)(q0_ + 32 + c0); \
        eg[SET][2] = *(const u8v*)(q1_ + c0);      eg[SET][3] = *(const u8v*)(q1_ + 32 + c0); \
        eg[SET][4] = *(const u8v*)(q2_ + c0);      eg[SET][5] = *(const u8v*)(q2_ + 32 + c0); \
        eg[SET][6] = *(const u8v*)(q3_ + c0);      eg[SET][7] = *(const u8v*)(q3_ + 32 + c0); }

#define BLEND(SET) { \
        s8v r0_, r1_; \
        _Pragma("unroll") \
        for (int j = 0; j < 8; j++) { \
            float va_ = gg[SET][0] * bu2f(eg[SET][0][j]) + gg[SET][1] * bu2f(eg[SET][2][j]) \
                      + gg[SET][2] * bu2f(eg[SET][4][j]) + gg[SET][3] * bu2f(eg[SET][6][j]); \
            float vb_ = gg[SET][0] * bu2f(eg[SET][1][j]) + gg[SET][1] * bu2f(eg[SET][3][j]) \
                      + gg[SET][2] * bu2f(eg[SET][5][j]) + gg[SET][3] * bu2f(eg[SET][7][j]); \
            r0_[j] = (short)f2bu(va_); \
            r1_[j] = (short)f2bu(vb_); \
        } \
        bf0 = r0_; bf1 = r1_; }

    GLOAD(0, 0);        // g(0) -> eg[0]
    GLOAD(1, 1);        // g(1) -> eg[1]
    BLEND(0);           // bf = blend(0)

#pragma unroll
    for (int kt = 0; kt < 9; kt++) {
        // A(kt) — issued first (FIFO: MFMA's wait leaves g(kt+2) in flight)
        const unsigned short* a = wcb + ln15 * 576 + kt * 64;
        s8v a0k0 = *(const s8v*)(a + c0);
        s8v a0k1 = *(const s8v*)(a + 32 + c0);
        s8v a1k0 = *(const s8v*)(a + 16 * 576 + c0);
        s8v a1k1 = *(const s8v*)(a + 16 * 576 + 32 + c0);
        s8v a2k0 = *(const s8v*)(a + 32 * 576 + c0);
        s8v a2k1 = *(const s8v*)(a + 32 * 576 + 32 + c0);
        s8v a3k0 = *(const s8v*)(a + 48 * 576 + c0);
        s8v a3k1 = *(const s8v*)(a + 48 * 576 + 32 + c0);
        // g(kt+2) into the set just consumed by blend(kt) — 2 iterations of cover
        if (kt < 7) GLOAD(kt & 1, kt + 2);
        // MFMA(kt): B from registers (blended last iteration)
        acc[0] = MF(a0k0, bf0, acc[0]);
        acc[1] = MF(a1k0, bf0, acc[1]);
        acc[2] = MF(a2k0, bf0, acc[2]);
        acc[3] = MF(a3k0, bf0, acc[3]);
        acc[0] = MF(a0k1, bf1, acc[0]);
        acc[1] = MF(a1k1, bf1, acc[1]);
        acc[2] = MF(a2k1, bf1, acc[2]);
        acc[3] = MF(a3k1, bf1, acc[3]);
        // blend(kt+1) from the other set (gathered 1-2 iterations ago)
        if (kt < 8) BLEND((kt + 1) & 1);
    }

    // epilogue: D col = pixel, row = oc
    int pix = hw0 + ln15;
    float* ob = out + (size_t)b * (OO * HW) + pix;
#pragma unroll
    for (int mt = 0; mt < 4; mt++) {
#pragma unroll
        for (int r = 0; r < 4; r++) {
            ob[(size_t)(mt * 16 + quad * 4 + r) * HW] = acc[mt][r];
        }
    }
}

extern "C" void kernel_launch(void* const* d_in, const int* in_sizes, int n_in,
                              void* d_out, int out_size, void* d_ws, size_t ws_size,
                              hipStream_t stream) {
    const float* x   = (const float*)d_in[0];
    const float* wp  = (const float*)d_in[1];
    const float* bp  = (const float*)d_in[2];
    const float* wm  = (const float*)d_in[3];
    const float* bm  = (const float*)d_in[4];
    const float* wcv = (const float*)d_in[5];
    float* ws = (float*)d_ws;
    float* out = (float*)d_out;

    hipLaunchKernelGGL(k_pxt, dim3(1248), dim3(256), 0, stream, x, wp, bp, wm, bm, wcv, ws);
    hipLaunchKernelGGL(k_main, dim3(4096), dim3(64), 0, stream, ws, out);
}

// Round 10
// 137.300 us; speedup vs baseline: 1.2520x; 1.2520x over previous
//
#include <hip/hip_runtime.h>
#include <hip/hip_bf16.h>

// DCNv2: B=4, C=64, H=W=128, O=64, KS=3, N=9, PAD=1. I/O float32.
#define BB 4
#define CC 64
#define HH 128
#define WW 128
#define OO 64
#define NN 9
#define HW 16384
#define HP 130
#define WP 130

// ---- ws layout (float-slot offsets) ----
#define WPMB_F  0
#define BPM_OFF 9216
#define WCB_F   9248
#define XT_F    27680

typedef __attribute__((ext_vector_type(8))) short s8v;
typedef __attribute__((ext_vector_type(8))) unsigned short u8v;
typedef __attribute__((ext_vector_type(4))) float f4v;

__device__ __forceinline__ unsigned short f2bu(float f) {   // fp32 -> bf16 bits (RNE)
    unsigned int b = __float_as_uint(f);
    return (unsigned short)((b + 0x7FFFu + ((b >> 16) & 1u)) >> 16);
}
__device__ __forceinline__ float bu2f(unsigned short u) {
    return __uint_as_float(((unsigned int)u) << 16);
}

#define MF(a, bb, c) __builtin_amdgcn_mfma_f32_16x16x32_bf16(a, bb, c, 0, 0, 0)

// blocks [0,1024): NCHW fp32 -> NHWC bf16 transpose via LDS tile.
// blocks [1024,1248): weight prep.
__global__ void __launch_bounds__(256) k_pxt(const float* __restrict__ x,
                                             const float* __restrict__ wp,
                                             const float* __restrict__ bp,
                                             const float* __restrict__ wm,
                                             const float* __restrict__ bm,
                                             const float* __restrict__ wcv,
                                             float* __restrict__ ws) {
    int blk = blockIdx.x;
    int t = threadIdx.x;
    if (blk >= 1024) {                       // ---- weight prep path ----
        int tid = (blk - 1024) * 256 + t;
        if (tid < 18432) {                   // wpmb [32][576]
            int r = tid / 576;
            int kk = tid % 576;              // kk = kt*64 + c
            int kt = kk >> 6;
            int c = kk & 63;
            int dy = kt / 3, dx = kt % 3;
            float v = 0.f;
            if (r < 18)       v = wp[((r * 64 + c) * 3 + dy) * 3 + dx];
            else if (r < 27)  v = wm[(((r - 18) * 64 + c) * 3 + dy) * 3 + dx];
            ((unsigned short*)(ws + WPMB_F))[tid] = f2bu(v);
        } else if (tid < 18459) {
            int i = tid - 18432;
            ws[BPM_OFF + i] = (i < 18) ? bp[i] : bm[i - 18];
        } else if (tid >= 20480) {           // wcb [64][576], tid < 57344 by grid
            int d = tid - 20480;
            int o = d / 576;
            int kk = d % 576;
            int kt = kk >> 6;
            int c = kk & 63;
            ((unsigned short*)(ws + WCB_F))[o * 576 + kk] = f2bu(wcv[(o * 64 + c) * 9 + kt]);
        }
        return;
    }
    // ---- transpose: block = 64 hw x 64 ch, tile stored [hw][c] ----
    __shared__ unsigned short tile[64][72];
    int sb = ((blk & 7) << 7) | (blk >> 3);   // XCD-chunked bijection on [0,1024)
    int b = sb >> 8;
    int hw0 = (sb & 255) * 64;
    unsigned short* xt = (unsigned short*)(ws + XT_F);

#pragma unroll
    for (int p = 0; p < 4; p++) {
        int c = p * 16 + (t >> 4);
        int h4 = (t & 15) * 4;
        float4 v = *(const float4*)(x + ((size_t)(b * 64 + c)) * HW + hw0 + h4);
        tile[h4 + 0][c] = f2bu(v.x);
        tile[h4 + 1][c] = f2bu(v.y);
        tile[h4 + 2][c] = f2bu(v.z);
        tile[h4 + 3][c] = f2bu(v.w);
    }
    __syncthreads();
#pragma unroll
    for (int p = 0; p < 2; p++) {
        int hw = p * 32 + (t >> 3);
        int cb = (t & 7) * 8;
        u8v o = *(const u8v*)(&tile[hw][cb]);
        *(u8v*)(xt + ((size_t)(b * HW + hw0 + hw)) * 64 + cb) = o;
    }
}

// Fused offset-conv + sampler + einsum with LDS BAND STAGING:
// the block's 5-row x 66-col x 64-ch neighborhood is staged ONCE (coalesced),
// then ALL gathers (phase-1 im2col rows AND phase-2 bilinear corners) are
// ds_read_b128 from LDS — no divergent VMEM, no TA serialization, no L1 thrash.
// Out-of-band samples (|offset| >~ 1; ~1e3 lanes grid-wide) take a predicated
// global fallback, preserving exact semantics for arbitrary offsets.
// Band slot stride 144B: bank-quad advance 1 per slot -> conflict-free b128.
__global__ void __launch_bounds__(256) k_main(const float* __restrict__ ws,
                                              float* __restrict__ out) {
    __shared__ alignas(16) unsigned short band[5 * 66 * 72];  // 47,520 B
    __shared__ float pxmL[4][3][NN][16];                      //  6,912 B

    int t = threadIdx.x;
    int lane = t & 63;
    int wv = t >> 6;
    int ln15 = lane & 15;
    int quad = lane >> 4;

    int braw = blockIdx.x;                   // 1024 = 8 XCD * 128: chunked swizzle
    int blk = ((braw & 7) << 7) | (braw >> 3);
    int b = blk >> 8;
    int hwB = (blk & 255) * 64;              // block pixel base (single image row)
    int h = hwB >> 7;                        // the row
    int w0 = hwB & 127;                      // 0 or 64
    int hw0 = hwB + wv * 16;                 // this wave's 16-pixel base

    const unsigned short* wpmb = (const unsigned short*)(ws + WPMB_F);
    const unsigned short* wcb  = (const unsigned short*)(ws + WCB_F);
    const unsigned short* xtb  = (const unsigned short*)(ws + XT_F) + (size_t)b * HW * 64;
    const float* bpm = ws + BPM_OFF;

    int wl = wv * 16 + ln15;                 // pixel w - w0 (0..63)
    int c0 = quad * 8;                       // k-slice base (halfwords)

    const u8v z8 = (u8v){0, 0, 0, 0, 0, 0, 0, 0};
    const f4v zf = (f4v){0.f, 0.f, 0.f, 0.f};

    // ---- stage band: rows h-2..h+2, cols w0-1..w0+64, zero-filled OOB ----
#pragma unroll
    for (int k = 0; k < 11; k++) {
        int idx = k * 256 + t;
        if (idx < 2640) {                    // 330 slots * 8 chunks of 16B
            int slot = idx >> 3, ch = idx & 7;
            int bi = slot / 66, j = slot - bi * 66;
            int r = h - 2 + bi, cc = w0 - 1 + j;
            u8v v = z8;
            if (((unsigned)r < 128u) && ((unsigned)cc < 128u))
                v = *(const u8v*)(xtb + (size_t)(r * 128 + cc) * 64 + ch * 8);
            *(u8v*)(band + slot * 72 + ch * 8) = v;
        }
    }
    __syncthreads();

    // ================= PHASE 1: offset/modulation GEMM (M=27, K=576) =================
    {
        f4v acc1[2];
        acc1[0] = zf;
        acc1[1] = zf;
#pragma unroll
        for (int kt = 0; kt < 9; kt++) {
            int dy = kt / 3, dx = kt % 3;
            const unsigned short* a = wpmb + ln15 * 576 + kt * 64;
            s8v a00 = *(const s8v*)(a + c0);
            s8v a01 = *(const s8v*)(a + 32 + c0);
            s8v a10 = *(const s8v*)(a + 16 * 576 + c0);
            s8v a11 = *(const s8v*)(a + 16 * 576 + 32 + c0);
            int s = ((dy + 1) * 66 + (wl + dx)) * 72 + c0;   // row h+dy-1, col w+dx-1
            s8v b0 = *(const s8v*)(band + s);
            s8v b1 = *(const s8v*)(band + s + 32);
            acc1[0] = MF(a00, b0, acc1[0]);
            acc1[1] = MF(a10, b0, acc1[1]);
            acc1[0] = MF(a01, b1, acc1[0]);
            acc1[1] = MF(a11, b1, acc1[1]);
        }
        // epilogue -> per-wave LDS pxm. pixel = ln15, oc = mt*16 + quad*4 + r
        int pwc = w0 + wl;                   // this lane's pixel w
#pragma unroll
        for (int mt = 0; mt < 2; mt++) {
#pragma unroll
            for (int r = 0; r < 4; r++) {
                int oc = mt * 16 + quad * 4 + r;
                if (oc < 27) {
                    float v = (mt ? acc1[1][r] : acc1[0][r]) + bpm[oc];
                    if (oc < 9) {
                        pxmL[wv][0][oc][ln15] = v + (float)(oc / 3 - 1) + (float)(h + 1);
                    } else if (oc < 18) {
                        int k = oc - 9;
                        pxmL[wv][1][k][ln15] = v + (float)(k % 3 - 1) + (float)(pwc + 1);
                    } else {
                        int k = oc - 18;
                        pxmL[wv][2][k][ln15] = 1.f / (1.f + __expf(-v));
                    }
                }
            }
        }
    }
    __builtin_amdgcn_wave_barrier();

    // ================= PHASE 2: sample + einsum GEMM (M=64, K=576) =================
    f4v acc[4];
#pragma unroll
    for (int mt = 0; mt < 4; mt++) acc[mt] = zf;

#pragma unroll
    for (int kt = 0; kt < 9; kt++) {
        // A(kt) — global, issued first; lands during desc+ds_read+blend
        const unsigned short* a = wcb + ln15 * 576 + kt * 64;
        s8v a0k0 = *(const s8v*)(a + c0);
        s8v a0k1 = *(const s8v*)(a + 32 + c0);
        s8v a1k0 = *(const s8v*)(a + 16 * 576 + c0);
        s8v a1k1 = *(const s8v*)(a + 16 * 576 + 32 + c0);
        s8v a2k0 = *(const s8v*)(a + 32 * 576 + c0);
        s8v a2k1 = *(const s8v*)(a + 32 * 576 + 32 + c0);
        s8v a3k0 = *(const s8v*)(a + 48 * 576 + c0);
        s8v a3k1 = *(const s8v*)(a + 48 * 576 + 32 + c0);

        // bilinear descriptor
        float px = pxmL[wv][0][kt][ln15];
        float py = pxmL[wv][1][kt][ln15];
        float mk = pxmL[wv][2][kt][ln15];
        float fx = floorf(px), fy = floorf(py);
        float pxc = fminf(fmaxf(px, 0.f), (float)(HP - 1));
        float pyc = fminf(fmaxf(py, 0.f), (float)(WP - 1));
        int qltx = (int)fminf(fmaxf(fx, 0.f), (float)(HP - 1));
        int qlty = (int)fminf(fmaxf(fy, 0.f), (float)(WP - 1));
        int qrbx = (int)fminf(fmaxf(fx + 1.f, 0.f), (float)(HP - 1));
        int qrby = (int)fminf(fmaxf(fy + 1.f, 0.f), (float)(WP - 1));

        float gltx = 1.f + ((float)qltx - pxc);
        float glty = 1.f + ((float)qlty - pyc);
        float grbx = 1.f - ((float)qrbx - pxc);
        float grby = 1.f - ((float)qrby - pyc);

        bool vlx = (qltx >= 1) && (qltx <= HH);
        bool vly = (qlty >= 1) && (qlty <= WW);
        bool vrx = (qrbx >= 1) && (qrbx <= HH);
        bool vry = (qrby >= 1) && (qrby <= WW);
        float g0 = (vlx && vly) ? gltx * glty * mk : 0.f;
        float g1 = (vrx && vry) ? grbx * grby * mk : 0.f;
        float g2 = (vlx && vry) ? gltx * grby * mk : 0.f;
        float g3 = (vrx && vly) ? grbx * glty * mk : 0.f;

        int xlt = min(max(qltx - 1, 0), HH - 1);
        int ylt = min(max(qlty - 1, 0), WW - 1);
        int xrb = min(max(qrbx - 1, 0), HH - 1);
        int yrb = min(max(qrby - 1, 0), WW - 1);

        // band indices + in-band tests
        int biL = xlt - h + 2, biR = xrb - h + 2;
        int jT = ylt - w0 + 1, jB = yrb - w0 + 1;
        int rl = ((unsigned)biL < 5u), rr = ((unsigned)biR < 5u);
        int ct = ((unsigned)jT < 66u), cb = ((unsigned)jB < 66u);
        int biLc = min(max(biL, 0), 4), biRc = min(max(biR, 0), 4);
        int jTc = min(max(jT, 0), 65), jBc = min(max(jB, 0), 65);
        int sLT = (biLc * 66 + jTc) * 72 + c0;
        int sRB = (biRc * 66 + jBc) * 72 + c0;
        int sLB = (biLc * 66 + jBc) * 72 + c0;
        int sRT = (biRc * 66 + jTc) * 72 + c0;

        u8v e0a = *(const u8v*)(band + sLT), e0b = *(const u8v*)(band + sLT + 32);
        u8v e1a = *(const u8v*)(band + sRB), e1b = *(const u8v*)(band + sRB + 32);
        u8v e2a = *(const u8v*)(band + sLB), e2b = *(const u8v*)(band + sLB + 32);
        u8v e3a = *(const u8v*)(band + sRT), e3b = *(const u8v*)(band + sRT + 32);

        // rare out-of-band fallback (exact semantics for arbitrary offsets)
        if (!__all(rl & rr & ct & cb)) {
            if (!(rl & ct)) {
                const unsigned short* q = xtb + (size_t)(xlt * 128 + ylt) * 64;
                e0a = *(const u8v*)(q + c0); e0b = *(const u8v*)(q + c0 + 32);
            }
            if (!(rr & cb)) {
                const unsigned short* q = xtb + (size_t)(xrb * 128 + yrb) * 64;
                e1a = *(const u8v*)(q + c0); e1b = *(const u8v*)(q + c0 + 32);
            }
            if (!(rl & cb)) {
                const unsigned short* q = xtb + (size_t)(xlt * 128 + yrb) * 64;
                e2a = *(const u8v*)(q + c0); e2b = *(const u8v*)(q + c0 + 32);
            }
            if (!(rr & ct)) {
                const unsigned short* q = xtb + (size_t)(xrb * 128 + ylt) * 64;
                e3a = *(const u8v*)(q + c0); e3b = *(const u8v*)(q + c0 + 32);
            }
        }

        // blend -> B-fragment (registers), same math/rounding as before
        s8v bf0, bf1;
#pragma unroll
        for (int j = 0; j < 8; j++) {
            float va = g0 * bu2f(e0a[j]) + g1 * bu2f(e1a[j])
                     + g2 * bu2f(e2a[j]) + g3 * bu2f(e3a[j]);
            float vb = g0 * bu2f(e0b[j]) + g1 * bu2f(e1b[j])
                     + g2 * bu2f(e2b[j]) + g3 * bu2f(e3b[j]);
            bf0[j] = (short)f2bu(va);
            bf1[j] = (short)f2bu(vb);
        }

        acc[0] = MF(a0k0, bf0, acc[0]);
        acc[1] = MF(a1k0, bf0, acc[1]);
        acc[2] = MF(a2k0, bf0, acc[2]);
        acc[3] = MF(a3k0, bf0, acc[3]);
        acc[0] = MF(a0k1, bf1, acc[0]);
        acc[1] = MF(a1k1, bf1, acc[1]);
        acc[2] = MF(a2k1, bf1, acc[2]);
        acc[3] = MF(a3k1, bf1, acc[3]);
    }

    // epilogue: D col = pixel, row = oc
    int pix = hw0 + ln15;
    float* ob = out + (size_t)b * (OO * HW) + pix;
#pragma unroll
    for (int mt = 0; mt < 4; mt++) {
#pragma unroll
        for (int r = 0; r < 4; r++) {
            ob[(size_t)(mt * 16 + quad * 4 + r) * HW] = acc[mt][r];
        }
    }
}

extern "C" void kernel_launch(void* const* d_in, const int* in_sizes, int n_in,
                              void* d_out, int out_size, void* d_ws, size_t ws_size,
                              hipStream_t stream) {
    const float* x   = (const float*)d_in[0];
    const float* wp  = (const float*)d_in[1];
    const float* bp  = (const float*)d_in[2];
    const float* wm  = (const float*)d_in[3];
    const float* bm  = (const float*)d_in[4];
    const float* wcv = (const float*)d_in[5];
    float* ws = (float*)d_ws;
    float* out = (float*)d_out;

    hipLaunchKernelGGL(k_pxt, dim3(1248), dim3(256), 0, stream, x, wp, bp, wm, bm, wcv, ws);
    hipLaunchKernelGGL(k_main, dim3(1024), dim3(256), 0, stream, ws, out);
}